// Round 1
// 25378.217 us; speedup vs baseline: 2.3449x; 2.3449x over previous
//
#include <hip/hip_runtime.h>
#include <cstdint>
#include <cstddef>

#define SEQ 512
#define BAT 64
#define DIM 1024
#define HID 1024
#define NLAYER 2
#define NGATE 4096  // 4*HID
#define EPS_LN 1e-5f
#define KSPLIT 8

// ---------------- setup ----------------

__global__ void init_hc_kernel(const float* __restrict__ h0,
                               const float* __restrict__ c0,
                               float* __restrict__ hbuf,
                               float* __restrict__ cbuf) {
    int i = blockIdx.x * blockDim.x + threadIdx.x; // 2*64*1024 total
    hbuf[i] = h0[i];
    cbuf[i] = c0[i];
}

// ---------------- per-step gates GEMM (fp32, 4x4 register-tiled) ----------------
// Grid (64 n-tiles, 8 k-slices), block 256.
// Block computes all 64 batches x 64 gate-cols for one K=256 slice.
//   ks 0..3 -> x half (A0, Wx, kbase = ks*256)
//   ks 4..7 -> h half (A1, Wh, kbase = (ks-4)*256)
// Thread (bq = tid>>4, nq = tid&15) owns a 4x4 output tile:
//   per 4 k-steps: 8 ds_read_b128 feed 64 FMA instructions.
__global__ __launch_bounds__(256) void gates_v2_kernel(
    const float* __restrict__ A0,   // [64][1024] fp32 (x_t or y_prev_t)
    const float* __restrict__ A1,   // [64][1024] fp32 (h)
    const float* __restrict__ Wx,   // [1024][4096] fp32 (layer slice)
    const float* __restrict__ Wh,   // [1024][4096] fp32 (layer slice)
    float* __restrict__ part)       // [8][64][4096]
{
    // stride 68 floats = 272 B: 16B-aligned rows (b128 ok), banks shift 4/row
    __shared__ float a_lds[64][68];   // [batch][k-chunk]
    __shared__ float w_lds[64][68];   // [k-chunk][n]

    const int nt = blockIdx.x;        // 0..63
    const int ks = blockIdx.y;        // 0..7
    const int n0t = nt * 64;
    const float* __restrict__ Asrc = (ks < 4) ? A0 : A1;
    const float* __restrict__ Wsrc = (ks < 4) ? Wx : Wh;
    const int kbase = (ks & 3) * 256;

    const int tid = threadIdx.x;
    const int nq = tid & 15;          // n-quad
    const int bq = tid >> 4;          // b-quad (16 quads = 64 batches)
    const int b0 = bq * 4;
    const int n0 = nq * 4;

    float acc[4][4];
    #pragma unroll
    for (int i = 0; i < 4; i++)
        #pragma unroll
        for (int j = 0; j < 4; j++) acc[i][j] = 0.f;

    // staging assignments
    const int sb = tid >> 2;            // A stage: batch row 0..63
    const int sk = (tid & 3) * 16;      // A stage: 16 consecutive k per thread
    const int wc = (tid & 15) * 4;      // W stage: col quad
    const int wk = tid >> 4;            // W stage: k row 0..15 (+16p)

    for (int kc = 0; kc < 256; kc += 64) {
        __syncthreads();
        // ---- stage A chunk: a_lds[b][k] = A[b][kbase+kc+k], 64x64 floats ----
        {
            const float* src = Asrc + (size_t)sb * 1024 + kbase + kc + sk;
            float4 v0 = *(const float4*)(src + 0);
            float4 v1 = *(const float4*)(src + 4);
            float4 v2 = *(const float4*)(src + 8);
            float4 v3 = *(const float4*)(src + 12);
            *(float4*)&a_lds[sb][sk + 0]  = v0;
            *(float4*)&a_lds[sb][sk + 4]  = v1;
            *(float4*)&a_lds[sb][sk + 8]  = v2;
            *(float4*)&a_lds[sb][sk + 12] = v3;
        }
        // ---- stage W chunk: w_lds[k][n] = W[kbase+kc+k][n0t+n], 64x64 floats ----
        {
            #pragma unroll
            for (int p = 0; p < 4; p++) {
                const int kr = wk + 16 * p;
                const float* src = Wsrc + (size_t)(kbase + kc + kr) * 4096 + n0t + wc;
                *(float4*)&w_lds[kr][wc] = *(const float4*)src;
            }
        }
        __syncthreads();

        // ---- inner: 64 k in groups of 4; 8 b128 reads per 64 FMAs ----
        #pragma unroll
        for (int kk = 0; kk < 64; kk += 4) {
            float av[4][4], wv[4][4];
            *(float4*)&av[0][0] = *(const float4*)&a_lds[b0 + 0][kk];
            *(float4*)&av[1][0] = *(const float4*)&a_lds[b0 + 1][kk];
            *(float4*)&av[2][0] = *(const float4*)&a_lds[b0 + 2][kk];
            *(float4*)&av[3][0] = *(const float4*)&a_lds[b0 + 3][kk];
            *(float4*)&wv[0][0] = *(const float4*)&w_lds[kk + 0][n0];
            *(float4*)&wv[1][0] = *(const float4*)&w_lds[kk + 1][n0];
            *(float4*)&wv[2][0] = *(const float4*)&w_lds[kk + 2][n0];
            *(float4*)&wv[3][0] = *(const float4*)&w_lds[kk + 3][n0];
            #pragma unroll
            for (int c = 0; c < 4; c++)
                #pragma unroll
                for (int i = 0; i < 4; i++)
                    #pragma unroll
                    for (int j = 0; j < 4; j++)
                        acc[i][j] = fmaf(av[i][c], wv[c][j], acc[i][j]);
        }
    }

    float* __restrict__ p = part + (size_t)ks * (BAT * NGATE);
    #pragma unroll
    for (int i = 0; i < 4; i++) {
        float4 o;
        o.x = acc[i][0]; o.y = acc[i][1]; o.z = acc[i][2]; o.w = acc[i][3];
        *(float4*)&p[(size_t)(b0 + i) * NGATE + n0t + n0] = o;
    }
}

// ---------------- per-step LN + cell update ----------------
__global__ __launch_bounds__(1024) void update_kernel(
    const float* __restrict__ part,    // [8][64][4096]
    const float* __restrict__ bias,    // [4096]  (layer slice)
    const float* __restrict__ gamma,   // [4][1024]
    const float* __restrict__ beta,    // [4][1024]
    float* __restrict__ cbuf,          // [64][1024]
    float* __restrict__ hbuf,          // [64][1024]
    float* __restrict__ y_out,         // d_out ys slot t
    float* __restrict__ hs_out,        // t==S-1: d_out hs slot, else null
    float* __restrict__ cs_out)
{
    int b = blockIdx.x;
    int j = threadIdx.x;
    float raw[4], s[4], q[4];
    #pragma unroll
    for (int g = 0; g < 4; g++) {
        int col = g * 1024 + j;
        float v = bias[col];
        #pragma unroll
        for (int p = 0; p < KSPLIT; p++)
            v += part[(size_t)p * (BAT * NGATE) + (size_t)b * 4096 + col];
        raw[g] = v; s[g] = v; q[g] = v * v;
    }
    #pragma unroll
    for (int off = 32; off > 0; off >>= 1) {
        #pragma unroll
        for (int g = 0; g < 4; g++) {
            s[g] += __shfl_down(s[g], off);
            q[g] += __shfl_down(q[g], off);
        }
    }
    __shared__ float red[16][8];
    __shared__ float stats[8];
    int wave = j >> 6, lane = j & 63;
    if (lane == 0) {
        #pragma unroll
        for (int g = 0; g < 4; g++) { red[wave][g] = s[g]; red[wave][4 + g] = q[g]; }
    }
    __syncthreads();
    if (j == 0) {
        float ts[8] = {0,0,0,0,0,0,0,0};
        for (int w = 0; w < 16; w++)
            for (int g = 0; g < 8; g++) ts[g] += red[w][g];
        #pragma unroll
        for (int g = 0; g < 4; g++) {
            float mu  = ts[g] * (1.0f / 1024.0f);
            float var = ts[4 + g] * (1.0f / 1024.0f) - mu * mu;
            stats[g] = mu;
            stats[4 + g] = rsqrtf(fmaxf(var, 0.0f) + EPS_LN);
        }
    }
    __syncthreads();
    float gh[4];
    #pragma unroll
    for (int g = 0; g < 4; g++) {
        int col = g * 1024 + j;
        gh[g] = (raw[g] - stats[g]) * stats[4 + g] * gamma[col] + beta[col];
    }
    float c_old = cbuf[b * 1024 + j];
    float ig = 1.f / (1.f + __expf(-gh[0]));
    float fg = 1.f / (1.f + __expf(-gh[1]));
    float og = 1.f / (1.f + __expf(-gh[2]));
    float c_new = fg * c_old + ig * tanhf(gh[3]);
    float h_new = og * tanhf(c_new);
    cbuf[b * 1024 + j] = c_new;
    hbuf[b * 1024 + j] = h_new;
    y_out[b * 1024 + j] = h_new;
    if (hs_out) { hs_out[b * 1024 + j] = h_new; cs_out[b * 1024 + j] = c_new; }
}

// ---------------- launch ----------------

extern "C" void kernel_launch(void* const* d_in, const int* in_sizes, int n_in,
                              void* d_out, int out_size, void* d_ws, size_t ws_size,
                              hipStream_t stream) {
    // All fp32, per the reference.
    const float* inputs = (const float*)d_in[0]; // (512,64,1024)
    const float* h0     = (const float*)d_in[1]; // (2,64,1024)
    const float* c0     = (const float*)d_in[2]; // (2,64,1024)
    const float* wx     = (const float*)d_in[3]; // (2,1024,4096)
    const float* wh     = (const float*)d_in[4]; // (2,1024,4096)
    const float* bias   = (const float*)d_in[5]; // (2,4096)
    const float* gamma  = (const float*)d_in[6]; // (2,4,1024)
    const float* beta   = (const float*)d_in[7]; // (2,4,1024)
    float* dout = (float*)d_out;

    // workspace: part 8 MiB + h/c state 1 MiB
    float* part  = (float*)d_ws;                     // 8*64*4096 f32 = 8 MiB
    float* hbuf  = part + (size_t)KSPLIT * BAT * NGATE; // 2*64*1024
    float* cbuf  = hbuf + NLAYER * BAT * HID;

    init_hc_kernel<<<512, 256, 0, stream>>>(h0, c0, hbuf, cbuf);

    const int BH = BAT * HID;         // 65536
    const int XOUT = SEQ * BAT * HID; // 33,554,432
    const size_t WL = (size_t)1024 * 4096; // per-layer weight stride
    for (int t = 0; t < SEQ; t++) {
        for (int l = 0; l < NLAYER; l++) {
            // layer 0 reads x_t; layer 1 reads y0_t just written into d_out slot t
            const float* a0 = (l == 0) ? (inputs + (size_t)t * BH)
                                       : (dout + (size_t)t * BH);
            gates_v2_kernel<<<dim3(64, KSPLIT), 256, 0, stream>>>(
                a0, hbuf + l * BH, wx + l * WL, wh + l * WL, part);
            update_kernel<<<64, 1024, 0, stream>>>(
                part,
                bias + l * 4096, gamma + l * 4096, beta + l * 4096,
                cbuf + l * BH, hbuf + l * BH,
                dout + (size_t)t * BH,   // l0 writes y0_t, l1 overwrites with y1_t
                (t == SEQ - 1) ? (dout + XOUT + l * BH) : nullptr,
                (t == SEQ - 1) ? (dout + XOUT + NLAYER * BH + l * BH) : nullptr);
        }
    }
}

// Round 3
// 25202.536 us; speedup vs baseline: 2.3613x; 1.0070x over previous
//
#include <hip/hip_runtime.h>
#include <cstdint>
#include <cstddef>

#define SEQ 512
#define BAT 64
#define DIM 1024
#define HID 1024
#define NLAYER 2
#define NGATE 4096  // 4*HID
#define EPS_LN 1e-5f
#define KSPLIT 12
#define PART_STRIDE (BAT * NGATE)  // 262144
#define LO_SCALE 4096.0f           // 2^12: keeps f16 low-order terms normal
#define LO_INV (1.0f / 4096.0f)

typedef __attribute__((ext_vector_type(8))) _Float16 f16x8;
typedef __attribute__((ext_vector_type(4))) float f32x4;

__device__ __forceinline__ unsigned short f2h(float f) {
    _Float16 h = (_Float16)f;             // round-to-nearest
    unsigned short u; __builtin_memcpy(&u, &h, 2); return u;
}
__device__ __forceinline__ float h2f(unsigned short u) {
    _Float16 h; __builtin_memcpy(&h, &u, 2); return (float)h;
}

// ---------------- setup ----------------

__global__ void init_hc_kernel(const float* __restrict__ h0,
                               const float* __restrict__ c0,
                               float* __restrict__ hbuf,
                               float* __restrict__ cbuf) {
    int i = blockIdx.x * blockDim.x + threadIdx.x;
    hbuf[i] = h0[i];
    cbuf[i] = c0[i];
}

// ---------------- one-time weight split + MFMA-fragment pack ----------------
// Packed layout per array (layer,mat,part): [nt=256][kc=32][lane=64][j=8] f16.
// Lane l reading (nt,kc) gets W[kc*32 + 8*(l>>4)+j][nt*16 + (l&15)] == the
// B-fragment of v_mfma_f32_16x16x32_f16. part0 = f16(W); part1 = f16(2^12 *
// (W - part0)) -- scaled so it stays in f16 normal range (MFMA flush safety).
__global__ __launch_bounds__(256) void prepack_w_kernel(
    const float* __restrict__ wx, const float* __restrict__ wh,
    unsigned short* __restrict__ wp)
{
    int gid = blockIdx.x * 256 + threadIdx.x;   // 2,097,152 threads
    int lane = gid & 63;
    int kc   = (gid >> 6) & 31;
    int nt   = (gid >> 11) & 255;
    int mat  = (gid >> 19) & 1;
    int l    = (gid >> 20) & 1;
    const float* src = (mat ? wh : wx) + (size_t)l * ((size_t)DIM * NGATE);
    int col = nt * 16 + (lane & 15);
    int kr0 = kc * 32 + 8 * (lane >> 4);
    unsigned hp[4], lp[4];
    #pragma unroll
    for (int i = 0; i < 4; i++) {
        float v0 = src[(size_t)(kr0 + 2 * i) * NGATE + col];
        float v1 = src[(size_t)(kr0 + 2 * i + 1) * NGATE + col];
        unsigned short h0 = f2h(v0), h1 = f2h(v1);
        unsigned short l0 = f2h(LO_SCALE * (v0 - h2f(h0)));
        unsigned short l1 = f2h(LO_SCALE * (v1 - h2f(h1)));
        hp[i] = (unsigned)h0 | ((unsigned)h1 << 16);
        lp[i] = (unsigned)l0 | ((unsigned)l1 << 16);
    }
    size_t inner = (((size_t)nt * 32 + kc) * 64 + lane) * 8;
    unsigned short* dh = wp + (((size_t)(l * 4 + mat * 2 + 0)) << 22) + inner;
    unsigned short* dl = wp + (((size_t)(l * 4 + mat * 2 + 1)) << 22) + inner;
    *(uint4*)dh = make_uint4(hp[0], hp[1], hp[2], hp[3]);
    *(uint4*)dl = make_uint4(lp[0], lp[1], lp[2], lp[3]);
}

// ---------------- per-step gates GEMM via f16x3 MFMA ----------------
// C[64,4096] = A[64,2048]*W[2048,4096], A=concat(x_t,h). Terms:
//   a1*w1 + a2'*w1/2^12   (dual-pass blocks, W1 read once, two accumulators)
// + a1*w2'/2^12           (lo-W blocks)
// Grid (32 n-blocks of 128 cols, 12 k-blocks). kb 0..7: W1 (x:0-3, h:4-7),
// K-slice 256. kb 8..11: W2 (x:8-9, h:10-11), K-slice 512.
// Block: 4 waves, wave owns M=32 x N=64 -> 2x4 mfma frags.
template<bool DUAL>
__device__ __forceinline__ void gates_body(
    const float* __restrict__ A0, const float* __restrict__ A1,
    const unsigned short* __restrict__ wpl, float* __restrict__ part,
    unsigned short* a_hi, unsigned short* a_lo)
{
    const int ntb = blockIdx.x;   // 0..31
    const int kb  = blockIdx.y;   // 0..11
    int mat, k0, klen;
    if (DUAL) { mat = kb >> 2;       k0 = (kb & 3) * 256; klen = 256; }
    else      { mat = (kb >> 1) & 1; k0 = (kb & 1) * 512; klen = 512; }
    const float* __restrict__ Asrc = mat ? A1 : A0;
    const unsigned short* __restrict__ Wbase =
        wpl + (((size_t)(mat * 2 + (DUAL ? 0 : 1))) << 22);

    const int tid  = threadIdx.x;
    const int lane = tid & 63;
    const int w    = tid >> 6;
    const int m0w  = (w >> 1) * 32;
    const int nh   = w & 1;
    const int lrow = lane & 15;
    const int lg   = lane >> 4;

    f32x4 acc[2][4];     // a1 * w
    f32x4 accl[2][4];    // a2' * w1 (dual only)
    #pragma unroll
    for (int mi = 0; mi < 2; mi++)
        #pragma unroll
        for (int ni = 0; ni < 4; ni++) {
            acc[mi][ni] = (f32x4){0.f, 0.f, 0.f, 0.f};
            accl[mi][ni] = (f32x4){0.f, 0.f, 0.f, 0.f};
        }

    const int sr = tid >> 2;          // staging row 0..63
    const int sq = (tid & 3) * 32;    // staging col base (floats)

    for (int kc0 = 0; kc0 < klen; kc0 += 128) {
        __syncthreads();
        {   // stage A chunk [64][128] fp32 -> f16 a1 (and scaled a2 if DUAL)
            const float* s = Asrc + (size_t)sr * 1024 + k0 + kc0 + sq;
            float4 q[8];
            #pragma unroll
            for (int i = 0; i < 8; i++) q[i] = *(const float4*)(s + 4 * i);
            unsigned hp[16], lp[16];
            #pragma unroll
            for (int i = 0; i < 8; i++) {
                unsigned short h0 = f2h(q[i].x), h1 = f2h(q[i].y);
                unsigned short h2 = f2h(q[i].z), h3 = f2h(q[i].w);
                hp[2 * i]     = (unsigned)h0 | ((unsigned)h1 << 16);
                hp[2 * i + 1] = (unsigned)h2 | ((unsigned)h3 << 16);
                if (DUAL) {
                    unsigned short l0 = f2h(LO_SCALE * (q[i].x - h2f(h0)));
                    unsigned short l1 = f2h(LO_SCALE * (q[i].y - h2f(h1)));
                    unsigned short l2 = f2h(LO_SCALE * (q[i].z - h2f(h2)));
                    unsigned short l3 = f2h(LO_SCALE * (q[i].w - h2f(h3)));
                    lp[2 * i]     = (unsigned)l0 | ((unsigned)l1 << 16);
                    lp[2 * i + 1] = (unsigned)l2 | ((unsigned)l3 << 16);
                }
            }
            unsigned base = sr * 256 + sq * 2;
            #pragma unroll
            for (int i = 0; i < 4; i++) {
                unsigned off = (base + 16 * i) ^ ((sr & 7) << 4);
                *(uint4*)((char*)a_hi + off) =
                    make_uint4(hp[4 * i], hp[4 * i + 1], hp[4 * i + 2], hp[4 * i + 3]);
                if (DUAL)
                    *(uint4*)((char*)a_lo + off) =
                        make_uint4(lp[4 * i], lp[4 * i + 1], lp[4 * i + 2], lp[4 * i + 3]);
            }
        }
        __syncthreads();

        const int kcgb = (k0 + kc0) >> 5;   // global k-chunk index
        #pragma unroll
        for (int kk = 0; kk < 4; kk++) {
            f16x8 bfr[4];
            #pragma unroll
            for (int ni = 0; ni < 4; ni++) {
                int ntg = ntb * 8 + nh * 4 + ni;
                const unsigned short* wptr =
                    Wbase + ((((size_t)ntg * 32) + (size_t)(kcgb + kk)) * 64 + lane) * 8;
                bfr[ni] = *(const f16x8*)wptr;   // coalesced 1KB wave read
            }
            f16x8 ah[2], al[2];
            #pragma unroll
            for (int mi = 0; mi < 2; mi++) {
                int row = m0w + mi * 16 + lrow;
                unsigned off = ((unsigned)(row * 256 + kk * 64 + lg * 16)) ^ ((row & 7) << 4);
                ah[mi] = *(const f16x8*)((const char*)a_hi + off);
                if (DUAL) al[mi] = *(const f16x8*)((const char*)a_lo + off);
            }
            #pragma unroll
            for (int mi = 0; mi < 2; mi++)
                #pragma unroll
                for (int ni = 0; ni < 4; ni++) {
                    acc[mi][ni] = __builtin_amdgcn_mfma_f32_16x16x32_f16(
                        ah[mi], bfr[ni], acc[mi][ni], 0, 0, 0);
                    if (DUAL)
                        accl[mi][ni] = __builtin_amdgcn_mfma_f32_16x16x32_f16(
                            al[mi], bfr[ni], accl[mi][ni], 0, 0, 0);
                }
        }
    }

    float* __restrict__ pp = part + (size_t)kb * PART_STRIDE;
    #pragma unroll
    for (int mi = 0; mi < 2; mi++)
        #pragma unroll
        for (int ni = 0; ni < 4; ni++) {
            int brow = m0w + mi * 16 + 4 * lg;
            int col  = ntb * 128 + nh * 64 + ni * 16 + lrow;
            #pragma unroll
            for (int r = 0; r < 4; r++) {
                float v = DUAL ? (acc[mi][ni][r] + accl[mi][ni][r] * LO_INV)
                               : (acc[mi][ni][r] * LO_INV);
                pp[(size_t)(brow + r) * NGATE + col] = v;
            }
        }
}

__global__ __launch_bounds__(256) void gates_mfma_kernel(
    const float* __restrict__ A0,   // [64][1024] fp32 (x_t or y_prev_t)
    const float* __restrict__ A1,   // [64][1024] fp32 (h)
    const unsigned short* __restrict__ wpl,  // packed weights, layer base
    float* __restrict__ part)       // [12][64][4096]
{
    __shared__ __align__(16) unsigned short a_hi[64 * 128];
    __shared__ __align__(16) unsigned short a_lo[64 * 128];
    if (blockIdx.y < 8) gates_body<true>(A0, A1, wpl, part, a_hi, a_lo);
    else                gates_body<false>(A0, A1, wpl, part, a_hi, a_lo);
}

// ---------------- per-step LN + cell update ----------------
__global__ __launch_bounds__(1024) void update_kernel(
    const float* __restrict__ part,    // [12][64][4096]
    const float* __restrict__ bias,    // [4096]  (layer slice)
    const float* __restrict__ gamma,   // [4][1024]
    const float* __restrict__ beta,    // [4][1024]
    float* __restrict__ cbuf,          // [64][1024]
    float* __restrict__ hbuf,          // [64][1024]
    float* __restrict__ y_out,         // d_out ys slot t
    float* __restrict__ hs_out,        // t==S-1: d_out hs slot, else null
    float* __restrict__ cs_out)
{
    int b = blockIdx.x;
    int j = threadIdx.x;
    float raw[4], s[4], q[4];
    #pragma unroll
    for (int g = 0; g < 4; g++) {
        int col = g * 1024 + j;
        float v = bias[col];
        #pragma unroll
        for (int p = 0; p < KSPLIT; p++)
            v += part[(size_t)p * PART_STRIDE + (size_t)b * 4096 + col];
        raw[g] = v; s[g] = v; q[g] = v * v;
    }
    #pragma unroll
    for (int off = 32; off > 0; off >>= 1) {
        #pragma unroll
        for (int g = 0; g < 4; g++) {
            s[g] += __shfl_down(s[g], off);
            q[g] += __shfl_down(q[g], off);
        }
    }
    __shared__ float red[16][8];
    __shared__ float stats[8];
    int wave = j >> 6, lane = j & 63;
    if (lane == 0) {
        #pragma unroll
        for (int g = 0; g < 4; g++) { red[wave][g] = s[g]; red[wave][4 + g] = q[g]; }
    }
    __syncthreads();
    if (j == 0) {
        float ts[8] = {0,0,0,0,0,0,0,0};
        for (int w = 0; w < 16; w++)
            for (int g = 0; g < 8; g++) ts[g] += red[w][g];
        #pragma unroll
        for (int g = 0; g < 4; g++) {
            float mu  = ts[g] * (1.0f / 1024.0f);
            float var = ts[4 + g] * (1.0f / 1024.0f) - mu * mu;
            stats[g] = mu;
            stats[4 + g] = rsqrtf(fmaxf(var, 0.0f) + EPS_LN);
        }
    }
    __syncthreads();
    float gh[4];
    #pragma unroll
    for (int g = 0; g < 4; g++) {
        int col = g * 1024 + j;
        gh[g] = (raw[g] - stats[g]) * stats[4 + g] * gamma[col] + beta[col];
    }
    float c_old = cbuf[b * 1024 + j];
    float ig = 1.f / (1.f + __expf(-gh[0]));
    float fg = 1.f / (1.f + __expf(-gh[1]));
    float og = 1.f / (1.f + __expf(-gh[2]));
    float c_new = fg * c_old + ig * tanhf(gh[3]);
    float h_new = og * tanhf(c_new);
    cbuf[b * 1024 + j] = c_new;
    hbuf[b * 1024 + j] = h_new;
    y_out[b * 1024 + j] = h_new;
    if (hs_out) { hs_out[b * 1024 + j] = h_new; cs_out[b * 1024 + j] = c_new; }
}

// ---------------- launch ----------------

extern "C" void kernel_launch(void* const* d_in, const int* in_sizes, int n_in,
                              void* d_out, int out_size, void* d_ws, size_t ws_size,
                              hipStream_t stream) {
    const float* inputs = (const float*)d_in[0]; // (512,64,1024)
    const float* h0     = (const float*)d_in[1]; // (2,64,1024)
    const float* c0     = (const float*)d_in[2]; // (2,64,1024)
    const float* wx     = (const float*)d_in[3]; // (2,1024,4096)
    const float* wh     = (const float*)d_in[4]; // (2,1024,4096)
    const float* bias   = (const float*)d_in[5]; // (2,4096)
    const float* gamma  = (const float*)d_in[6]; // (2,4,1024)
    const float* beta   = (const float*)d_in[7]; // (2,4,1024)
    float* dout = (float*)d_out;

    // workspace: packed f16 weights 64 MiB + part 12 MiB + h/c 1 MiB = 77 MiB
    unsigned short* wp = (unsigned short*)d_ws;
    float* part = (float*)(wp + ((size_t)8 << 22));
    float* hbuf = part + (size_t)KSPLIT * PART_STRIDE;
    float* cbuf = hbuf + NLAYER * BAT * HID;

    prepack_w_kernel<<<8192, 256, 0, stream>>>(wx, wh, wp);
    init_hc_kernel<<<512, 256, 0, stream>>>(h0, c0, hbuf, cbuf);

    const int BH = BAT * HID;         // 65536
    const int XOUT = SEQ * BAT * HID; // 33,554,432
    for (int t = 0; t < SEQ; t++) {
        for (int l = 0; l < NLAYER; l++) {
            const float* a0 = (l == 0) ? (inputs + (size_t)t * BH)
                                       : (dout + (size_t)t * BH);
            gates_mfma_kernel<<<dim3(32, KSPLIT), 256, 0, stream>>>(
                a0, hbuf + l * BH, wp + ((size_t)l << 24), part);
            update_kernel<<<64, 1024, 0, stream>>>(
                part,
                bias + l * 4096, gamma + l * 4096, beta + l * 4096,
                cbuf + l * BH, hbuf + l * BH,
                dout + (size_t)t * BH,
                (t == SEQ - 1) ? (dout + XOUT + l * BH) : nullptr,
                (t == SEQ - 1) ? (dout + XOUT + NLAYER * BH + l * BH) : nullptr);
        }
    }
}